// Round 9
// baseline (2152.367 us; speedup 1.0000x reference)
//
#include <hip/hip_runtime.h>
#include <hip/hip_bf16.h>

#define BATCH 256
#define TLEN  512
#define HID   256
#define NT    512          // thread (jj, half): jj = tid&255 owns hidden unit jj; half = K-split
#define NPAIR 64           // fp16 pairs per thread per gate (half of K=256)

typedef _Float16 v2h __attribute__((ext_vector_type(2)));

__device__ __forceinline__ int pack_pair(float x, float y) {
  union { int i; v2h h; } cv; cv.h[0] = (_Float16)x; cv.h[1] = (_Float16)y; return cv.i;
}

__device__ __forceinline__ float fast_sigmoid(float x) {
  float e = __expf(-x);
  return __builtin_amdgcn_rcpf(1.0f + e);
}
__device__ __forceinline__ float fast_tanh(float x) {
  float e = __expf(-2.0f * x);
  return (1.0f - e) * __builtin_amdgcn_rcpf(1.0f + e);
}

// 64 triples (k, k+64, k+128): AGPR indices for gate r (a0-63), z (a64-127), n (a128-191)
#define REP64T(M) \
  M(0,64,128) M(1,65,129) M(2,66,130) M(3,67,131) M(4,68,132) M(5,69,133) \
  M(6,70,134) M(7,71,135) M(8,72,136) M(9,73,137) M(10,74,138) M(11,75,139) \
  M(12,76,140) M(13,77,141) M(14,78,142) M(15,79,143) M(16,80,144) M(17,81,145) \
  M(18,82,146) M(19,83,147) M(20,84,148) M(21,85,149) M(22,86,150) M(23,87,151) \
  M(24,88,152) M(25,89,153) M(26,90,154) M(27,91,155) M(28,92,156) M(29,93,157) \
  M(30,94,158) M(31,95,159) M(32,96,160) M(33,97,161) M(34,98,162) M(35,99,163) \
  M(36,100,164) M(37,101,165) M(38,102,166) M(39,103,167) M(40,104,168) M(41,105,169) \
  M(42,106,170) M(43,107,171) M(44,108,172) M(45,109,173) M(46,110,174) M(47,111,175) \
  M(48,112,176) M(49,113,177) M(50,114,178) M(51,115,179) M(52,116,180) M(53,117,181) \
  M(54,118,182) M(55,119,183) M(56,120,184) M(57,121,185) M(58,122,186) M(59,123,187) \
  M(60,124,188) M(61,125,189) M(62,126,190) M(63,127,191)

// Park weight word k of gates r/z/n into fixed AGPRs a{i0}/a{i1}/a{i2}.
// Hard-coded register names: the RA never tracks these values -> cannot spill.
#define LOADC3(i0,i1,i2) { \
    float2 t; int p; \
    t = r0[i0]; p = pack_pair(t.x, t.y); \
    asm volatile("v_accvgpr_write_b32 a" #i0 ", %0" :: "v"(p) : "a" #i0); \
    t = z0[i0]; p = pack_pair(t.x, t.y); \
    asm volatile("v_accvgpr_write_b32 a" #i1 ", %0" :: "v"(p) : "a" #i1); \
    t = n0[i0]; p = pack_pair(t.x, t.y); \
    asm volatile("v_accvgpr_write_b32 a" #i2 ", %0" :: "v"(p) : "a" #i2); \
  }

// One h-word (readlane -> SGPR, legal VOP3P scalar src) x 3 gates:
// v_accvgpr_read pulls the parked weight, v_dot2_f32_f16 accumulates fp32.
// r/z/n rotation gives dependency distance >= 4 instrs per acc chain.
#define DOTC3(i0,i1,i2) { \
    int hv = __builtin_amdgcn_readlane(hword, i0); \
    asm volatile("v_accvgpr_read_b32 %1, a" #i0 "\n\t" \
                 "v_dot2_f32_f16 %0, %2, %1, %0" \
                 : "+v"(ar), "=&v"(tmp) : "s"(hv)); \
    asm volatile("v_accvgpr_read_b32 %1, a" #i1 "\n\t" \
                 "v_dot2_f32_f16 %0, %2, %1, %0" \
                 : "+v"(az), "=&v"(tmp) : "s"(hv)); \
    asm volatile("v_accvgpr_read_b32 %1, a" #i2 "\n\t" \
                 "v_dot2_f32_f16 %0, %2, %1, %0" \
                 : "+v"(an), "=&v"(tmp) : "s"(hv)); \
  }

#define DOTS(Dr, Dz, Dn) { \
    int hword = ((const int*)h16)[half * NPAIR + lane]; \
    float ar = 0.f, az = 0.f, an = 0.f; int tmp; \
    REP64T(DOTC3) \
    Dr = ar; Dz = az; Dn = an; \
  }

#define LOAD_WEIGHTS(WHH, WIH, BIH, BHH)                                        \
  {                                                                             \
    const float2* r0 = (const float2*)((WHH) + (size_t)(0 * HID + jj) * HID) + half * NPAIR; \
    const float2* z0 = (const float2*)((WHH) + (size_t)(1 * HID + jj) * HID) + half * NPAIR; \
    const float2* n0 = (const float2*)((WHH) + (size_t)(2 * HID + jj) * HID) + half * NPAIR; \
    REP64T(LOADC3)                                                              \
    wih_r = (WIH)[jj]; wih_z = (WIH)[HID + jj]; wih_n = (WIH)[2 * HID + jj];    \
    br  = (BIH)[jj] + (BHH)[jj];                                                \
    bz  = (BIH)[HID + jj] + (BHH)[HID + jj];                                    \
    bin = (BIH)[2 * HID + jj];                                                  \
    bhn = (BHH)[2 * HID + jj];                                                  \
  }

__global__ void __launch_bounds__(NT)
gru_ae_kernel(
    const float* __restrict__ x,
    const float* __restrict__ w_ih_enc, const float* __restrict__ w_hh_enc,
    const float* __restrict__ b_ih_enc, const float* __restrict__ b_hh_enc,
    const float* __restrict__ w_ih_dec, const float* __restrict__ w_hh_dec,
    const float* __restrict__ b_ih_dec, const float* __restrict__ b_hh_dec,
    const float* __restrict__ w_dense, const float* __restrict__ b_dense,
    float* __restrict__ out)
{
  const int b    = blockIdx.x;
  const int tid  = threadIdx.x;
  const int jj   = tid & (HID - 1);   // hidden unit owned (for weights/gate math)
  const int half = tid >> 8;          // 0 or 1: which K-half (wave-uniform)
  const int lane = tid & 63;

  __shared__ __align__(4) _Float16 h16[HID];    // fp16 h, read as 128 u32 pairs
  __shared__ float pr[NT], pz[NT], pn[NT];      // partial dots
  __shared__ float red[HID];                    // dense reduction scratch
  __shared__ float xbuf[TLEN];
  __shared__ float obuf[TLEN];
  __shared__ float xcur_s;

  for (int t = tid; t < TLEN; t += NT) xbuf[t] = x[(size_t)b * TLEN + t];
  if (tid < HID) h16[tid] = (_Float16)0.0f;
  float hreg   = 0.0f;                               // fp32 master h[jj] (tid<HID)
  float wd_reg = (tid < HID) ? w_dense[jj] : 0.0f;
  const float bd = b_dense[0];

  float wih_r, wih_z, wih_n, br, bz, bin, bhn;

  LOAD_WEIGHTS(w_hh_enc, w_ih_enc, b_ih_enc, b_hh_enc);
  __syncthreads();

  // ---- encoder: 512 steps, 2 barriers each ----
  for (int t = 0; t < TLEN; ++t) {
    float Dr, Dz, Dn;
    DOTS(Dr, Dz, Dn);
    pr[tid] = Dr; pz[tid] = Dz; pn[tid] = Dn;
    __syncthreads();                                  // (a) partials visible
    if (tid < HID) {
      float dr = pr[tid] + pr[tid + HID];
      float dz = pz[tid] + pz[tid + HID];
      float dn = pn[tid] + pn[tid + HID];
      float xt = xbuf[t];
      float r  = fast_sigmoid(fmaf(xt, wih_r, br) + dr);
      float z  = fast_sigmoid(fmaf(xt, wih_z, bz) + dz);
      float n  = fast_tanh(fmaf(r, dn + bhn, fmaf(xt, wih_n, bin)));
      float hn = n + z * (hreg - n);
      hreg = hn;
      h16[tid] = (_Float16)hn;
    }
    __syncthreads();                                  // (b) h16 visible
  }

  // ---- switch to decoder weights (overwrite the same AGPRs) ----
  LOAD_WEIGHTS(w_hh_dec, w_ih_dec, b_ih_dec, b_hh_dec);

  // seed dense reduction with encoder final h
  if (tid < HID) red[tid] = hreg * wd_reg;
  __syncthreads();

  // ---- decoder: 512 autoregressive steps ----
  for (int t = 0; t < TLEN; ++t) {
    // wave 0: reduce red -> x for THIS step (x0 at t=0; output xs[t-1] for t>0)
    if (tid < 64) {
      float s = (red[tid] + red[tid + 64]) + (red[tid + 128] + red[tid + 192]);
      s += __shfl_down(s, 32);
      s += __shfl_down(s, 16);
      s += __shfl_down(s, 8);
      s += __shfl_down(s, 4);
      s += __shfl_down(s, 2);
      s += __shfl_down(s, 1);
      if (tid == 0) {
        float xn = s + bd;
        xcur_s = xn;
        if (t > 0) obuf[t - 1] = xn;
      }
    }
    float Dr, Dz, Dn;
    DOTS(Dr, Dz, Dn);
    pr[tid] = Dr; pz[tid] = Dz; pn[tid] = Dn;
    __syncthreads();                                  // (a)
    if (tid < HID) {
      float dr = pr[tid] + pr[tid + HID];
      float dz = pz[tid] + pz[tid + HID];
      float dn = pn[tid] + pn[tid + HID];
      float xt = xcur_s;
      float r  = fast_sigmoid(fmaf(xt, wih_r, br) + dr);
      float z  = fast_sigmoid(fmaf(xt, wih_z, bz) + dz);
      float n  = fast_tanh(fmaf(r, dn + bhn, fmaf(xt, wih_n, bin)));
      float hn = n + z * (hreg - n);
      hreg = hn;
      h16[tid] = (_Float16)hn;
      red[tid] = hn * wd_reg;
    }
    __syncthreads();                                  // (b)
  }

  // final output xs[T-1]
  if (tid < 64) {
    float s = (red[tid] + red[tid + 64]) + (red[tid + 128] + red[tid + 192]);
    s += __shfl_down(s, 32);
    s += __shfl_down(s, 16);
    s += __shfl_down(s, 8);
    s += __shfl_down(s, 4);
    s += __shfl_down(s, 2);
    s += __shfl_down(s, 1);
    if (tid == 0) obuf[TLEN - 1] = s + bd;
  }
  __syncthreads();

  // out[b, t] = xs[T-1-t]  (flip)
  for (int t = tid; t < TLEN; t += NT)
    out[(size_t)b * TLEN + t] = obuf[TLEN - 1 - t];
}

extern "C" void kernel_launch(void* const* d_in, const int* in_sizes, int n_in,
                              void* d_out, int out_size, void* d_ws, size_t ws_size,
                              hipStream_t stream) {
  const float* x        = (const float*)d_in[0];
  const float* w_ih_enc = (const float*)d_in[1];
  const float* w_hh_enc = (const float*)d_in[2];
  const float* b_ih_enc = (const float*)d_in[3];
  const float* b_hh_enc = (const float*)d_in[4];
  const float* w_ih_dec = (const float*)d_in[5];
  const float* w_hh_dec = (const float*)d_in[6];
  const float* b_ih_dec = (const float*)d_in[7];
  const float* b_hh_dec = (const float*)d_in[8];
  const float* w_dense  = (const float*)d_in[9];
  const float* b_dense  = (const float*)d_in[10];
  float* out = (float*)d_out;

  hipLaunchKernelGGL(gru_ae_kernel, dim3(BATCH), dim3(NT), 0, stream,
                     x, w_ih_enc, w_hh_enc, b_ih_enc, b_hh_enc,
                     w_ih_dec, w_hh_dec, b_ih_dec, b_hh_dec,
                     w_dense, b_dense, out);
}